// Round 9
// baseline (890.369 us; speedup 1.0000x reference)
//
#include <hip/hip_runtime.h>
#include <hip/hip_bf16.h>
#include <hip/hip_cooperative_groups.h>

namespace cg = cooperative_groups;

#define NN 100000
#define EE 1600000
#define HH 128
#define GG 64
#define LL 3
#define BN_EPS 1e-5f
#define NT 391              // ceil(EE/4096) edge tiles == ceil(NN/256) node tiles
#define CHW 392             // lbu row width (NT+1)
#define CAP 6144            // per-tile csr slab capacity (pad-8)
#define PN 32               // pool chunk
#define NTG 391             // ceil(NN/256) row tiles for the 1024-thread gemm
#define SMEM_BYTES 55552

typedef __hip_bfloat16 bf16;
typedef __attribute__((ext_vector_type(8))) short short8;
typedef __attribute__((ext_vector_type(4))) float floatx4;

__device__ __forceinline__ float lo16(unsigned v) { return __uint_as_float(v << 16); }
__device__ __forceinline__ float hi16(unsigned v) { return __uint_as_float(v & 0xffff0000u); }
__device__ __forceinline__ unsigned short f2b(float v) {
    bf16 h = __float2bfloat16(v);
    return *(unsigned short*)&h;
}
__device__ __forceinline__ unsigned pack2(float a, float b) {
    return (unsigned)f2b(a) | ((unsigned)f2b(b) << 16);
}
__device__ __forceinline__ int geti(const int* __restrict__ p, int i, int f) {
    return f ? p[2 * i] : p[i];
}

struct MegaArgs {
    const int* ei; const int* batch; const float* x;
    const float* conv_w; const float* conv_b;
    const float* bn_g; const float* bn_b; const float* bn_m; const float* bn_v;
    const float* nw1; const float* nb1; const float* nw2; const float* nb2;
    const float* gw1; const float* gb1; const float* gw2; const float* gb2;
    float* out;
    unsigned short* hb; unsigned short* tb;
    unsigned* chunk; unsigned* csr; unsigned short* lbu;
    int* offs; int* cnt; float* dinv;
    float* bnA; float* bnB; float* gsum; float* gcnt;
    unsigned short* cwB; unsigned short* n1B; int* flag;
};

// ---- phase 1: prep + block-local edge tile sort (r8 k_part body) ---------
__device__ void phase_part(char* smem, int NB, int f, const MegaArgs& A) {
    int* lcnt = (int*)smem;                                // NT ints
    int* wsum = (int*)(smem + 1568);                       // 8
    unsigned short* lbs = (unsigned short*)(smem + 1600);  // CHW
    unsigned* sorted = (unsigned*)(smem + 2384);           // 4096
    int t = threadIdx.x;
    // one-shot prep, spread over the grid (NB*1024 >= 256K > all arrays)
    int gi = blockIdx.x * 1024 + t;
    if (gi < LL * HH * HH) A.cwB[gi] = f2b(A.conv_w[gi]);
    if (gi < 64 * HH) A.n1B[gi] = f2b(A.nw1[gi]);
    if (gi < LL * HH) {
        float Av = A.bn_g[gi] * rsqrtf(A.bn_v[gi] + BN_EPS);
        A.bnA[gi] = Av;
        A.bnB[gi] = (A.conv_b[gi] - A.bn_m[gi]) * Av + A.bn_b[gi];
    }
    if (gi < GG * HH) A.gsum[gi] = 0.f;
    if (gi < GG) A.gcnt[gi] = 0.f;
    if (gi < 64) ((unsigned*)A.tb)[(size_t)NN * 64 + gi] = 0u;  // zero pad-row
    if (blockIdx.x == 0 && t == 0) *A.flag = f;
    for (int T = blockIdx.x; T < NT; T += NB) {
        int e0 = T * 4096;
        int nume = EE - e0 < 4096 ? EE - e0 : 4096;
        for (int i = t; i < NT; i += 1024) lcnt[i] = 0;
        __syncthreads();
        unsigned pk[4]; int ml[4], mt[4];
#pragma unroll
        for (int i = 0; i < 4; i++) {
            int li = i * 1024 + t;
            if (li < nume) {
                int e = e0 + li;
                int src = geti(A.ei, e, f), dst = geti(A.ei, EE + e, f);
                mt[i] = dst >> 8;
                pk[i] = ((unsigned)src << 8) | (unsigned)(dst & 255);
                ml[i] = atomicAdd(&lcnt[mt[i]], 1);
            }
        }
        __syncthreads();
        int own = 0, x = 0;
        if (t < 512) { own = t < NT ? lcnt[t] : 0; x = own; }
#pragma unroll
        for (int off = 1; off < 64; off <<= 1) {
            int y = __shfl_up(x, off);
            if ((t & 63) >= off) x += y;
        }
        if (t < 512 && (t & 63) == 63) wsum[t >> 6] = x;
        __syncthreads();
        if (t < NT) {
            int pre = 0, w = t >> 6;
#pragma unroll
            for (int i = 0; i < 7; i++) if (i < w) pre += wsum[i];
            lbs[t] = (unsigned short)(pre + x - own);
        }
        if (t == 0) lbs[NT] = (unsigned short)nume;
        __syncthreads();
#pragma unroll
        for (int i = 0; i < 4; i++) {
            int li = i * 1024 + t;
            if (li < nume) sorted[(int)lbs[mt[i]] + ml[i]] = pk[i];
        }
        if (t < CHW) A.lbu[T * CHW + t] = lbs[t];
        __syncthreads();
        for (int idx = t; idx < nume; idx += 1024)
            A.chunk[e0 + idx] = sorted[idx];
    }
}

// ---- phase 2: per-tile CSR, 8-padded segments (r8 k_csr body) ------------
__device__ void phase_csr(char* smem, int NB, const MegaArgs& A) {
    unsigned* stage = (unsigned*)smem;                 // CAP
    unsigned* outb  = (unsigned*)(smem + 24576);       // CAP
    int* segso = (int*)(smem + 49152);                 // 512
    int* segst = (int*)(smem + 51200);                 // 512
    int* hist  = (int*)(smem + 53248);                 // 256
    int* cur   = (int*)(smem + 54272);                 // 256
    int* wsum  = (int*)(smem + 55296);                 // 8
    int* w2x   = (int*)(smem + 55328);                 // 4
    int* s_nep = (int*)(smem + 55344);                 // 1
    int t = threadIdx.x;
    for (int T = blockIdx.x; T < NT; T += NB) {
        int st = 0, rl = 0;
        if (t < NT) {
            int s0 = A.lbu[t * CHW + T];
            int s1 = A.lbu[t * CHW + T + 1];
            st = t * 4096 + s0;
            rl = s1 - s0;
        }
        int x = (t < 512) ? rl : 0;
#pragma unroll
        for (int off = 1; off < 64; off <<= 1) {
            int y = __shfl_up(x, off);
            if ((t & 63) >= off) x += y;
        }
        if (t < 512 && (t & 63) == 63) wsum[t >> 6] = x;
        if (t < 256) hist[t] = 0;
        __syncthreads();
        int tot = 0;
#pragma unroll
        for (int i = 0; i < 8; i++) tot += wsum[i];
        int ne = tot > CAP ? CAP : tot;
        if (t < 512) {
            int pre = 0, w = t >> 6;
#pragma unroll
            for (int i = 0; i < 7; i++) if (i < w) pre += wsum[i];
            segso[t] = pre + x - rl;
            segst[t] = st;
        }
        __syncthreads();
        for (int i = t; i < ne; i += 1024) {
            int lo = 0;
#pragma unroll
            for (int b = 256; b; b >>= 1) {
                int nlo = lo + b;
                if (nlo < 512 && segso[nlo] <= i) lo = nlo;
            }
            stage[i] = A.chunk[segst[lo] + (i - segso[lo])];
        }
        __syncthreads();
        for (int i = t; i < ne; i += 1024)
            atomicAdd(&hist[stage[i] & 255u], 1);
        __syncthreads();
        int c = 0, pc = 0, x2 = 0;
        if (t < 256) {
            c = hist[t];
            pc = (c + 7) & ~7;
            x2 = pc;
        }
#pragma unroll
        for (int off = 1; off < 64; off <<= 1) {
            int y = __shfl_up(x2, off);
            if ((t & 63) >= off) x2 += y;
        }
        if (t < 256 && (t & 63) == 63) w2x[t >> 6] = x2;
        __syncthreads();
        if (t < 256) {
            int pre = 0, w = t >> 6;
#pragma unroll
            for (int i = 0; i < 3; i++) if (i < w) pre += w2x[i];
            int stn = pre + x2 - pc;
            cur[t] = stn;
            int node = T * 256 + t;
            if (node < NN) {
                A.offs[node] = T * CAP + stn;
                A.cnt[node] = c;
                A.dinv[node] = rsqrtf(1.0f + (float)c);
            }
            for (int i = stn + c; i < stn + pc && i < CAP; i++)
                outb[i] = NN;
        }
        if (t == 0) {
            int tt = w2x[0] + w2x[1] + w2x[2] + w2x[3];
            *s_nep = tt < CAP ? tt : CAP;
        }
        __syncthreads();
        for (int i = t; i < ne; i += 1024) {
            unsigned p = stage[i];
            int q = atomicAdd(&cur[p & 255u], 1);
            if (q < CAP) outb[q] = p >> 8;
        }
        __syncthreads();
        int nep = *s_nep;
        for (int i = t; i < nep; i += 1024)
            A.csr[(size_t)T * CAP + i] = outb[i];
        __syncthreads();
    }
}

// ---- gemm phase: 1024 threads, 256-row tiles, W staged ONCE per phase ----
template<typename AT, int NC, bool FUSE>
__device__ void phase_gemm(char* smem, int NB, const AT* __restrict__ in,
        const unsigned short* __restrict__ Wb, const float* __restrict__ bias,
        unsigned short* __restrict__ outh, int do_relu,
        const float* __restrict__ scale, const float* __restrict__ w2,
        const float* __restrict__ b2v, float* __restrict__ out2f) {
    char* sB = smem;
    int t = threadIdx.x;
    int wave = t >> 6, lane = t & 63, ln = lane & 15, q = lane >> 4;
    const short8* wsrc = (const short8*)Wb;
    for (int i = t; i < NC * 16; i += 1024)
        *(short8*)(sB + (i >> 4) * 272 + (i & 15) * 16) = wsrc[i];
    __syncthreads();
    for (int T = blockIdx.x; T < NTG; T += NB) {
        int r0 = T * 256 + wave * 16;
        int row = r0 + ln;
        int rr = row < NN ? row : NN - 1;
        short8 a[4];
        if constexpr (sizeof(AT) == 2) {
            const short8* ap = (const short8*)(in + (size_t)rr * HH);
#pragma unroll
            for (int kt = 0; kt < 4; kt++) a[kt] = ap[kt * 4 + q];
        } else {
            const float4* ap = (const float4*)(in + (size_t)rr * HH);
#pragma unroll
            for (int kt = 0; kt < 4; kt++) {
                float4 f0 = ap[(kt * 4 + q) * 2];
                float4 f1 = ap[(kt * 4 + q) * 2 + 1];
                a[kt][0] = (short)f2b(f0.x); a[kt][1] = (short)f2b(f0.y);
                a[kt][2] = (short)f2b(f0.z); a[kt][3] = (short)f2b(f0.w);
                a[kt][4] = (short)f2b(f1.x); a[kt][5] = (short)f2b(f1.y);
                a[kt][6] = (short)f2b(f1.z); a[kt][7] = (short)f2b(f1.w);
            }
        }
        float scl[4];
        if constexpr (!FUSE) {
#pragma unroll
            for (int reg = 0; reg < 4; reg++) {
                int orow = r0 + q * 4 + reg;
                scl[reg] = scale ? scale[orow < NN ? orow : NN - 1] : 1.f;
            }
        }
        float p0[4], p1[4];
        if constexpr (FUSE) {
#pragma unroll
            for (int r = 0; r < 4; r++) { p0[r] = 0.f; p1[r] = 0.f; }
        }
#pragma unroll
        for (int ct = 0; ct < NC / 16; ct++) {
            int c = ct * 16 + ln;
            floatx4 acc = {0.f, 0.f, 0.f, 0.f};
#pragma unroll
            for (int kt = 0; kt < 4; kt++) {
                short8 b = *(const short8*)(sB + (size_t)c * 272 + kt * 64 + q * 16);
                acc = __builtin_amdgcn_mfma_f32_16x16x32_bf16(a[kt], b, acc, 0, 0, 0);
            }
            float bv = bias ? bias[c] : 0.f;
            if constexpr (FUSE) {
                float wa = w2[c], wb = w2[64 + c];
#pragma unroll
                for (int reg = 0; reg < 4; reg++) {
                    float v = fmaxf(acc[reg] + bv, 0.f);
                    p0[reg] = fmaf(v, wa, p0[reg]);
                    p1[reg] = fmaf(v, wb, p1[reg]);
                }
            } else {
#pragma unroll
                for (int reg = 0; reg < 4; reg++) {
                    int orow = r0 + q * 4 + reg;   // C/D: col=lane&15, row=quad*4+reg
                    if (orow < NN) {
                        float v = acc[reg] + bv;
                        if (do_relu) v = fmaxf(v, 0.f);
                        outh[(size_t)orow * NC + c] = f2b(v * scl[reg]);
                    }
                }
            }
        }
        if constexpr (FUSE) {
#pragma unroll
            for (int off = 1; off < 16; off <<= 1) {
#pragma unroll
                for (int r = 0; r < 4; r++) {
                    p0[r] += __shfl_xor(p0[r], off);
                    p1[r] += __shfl_xor(p1[r], off);
                }
            }
            if (ln == 0) {
                float ba = b2v[0], bb = b2v[1];
#pragma unroll
                for (int reg = 0; reg < 4; reg++) {
                    int orow = r0 + q * 4 + reg;
                    if (orow < NN)
                        ((float2*)out2f)[orow] = make_float2(p0[reg] + ba, p1[reg] + bb);
                }
            }
        }
    }
}

// ---- aggr phase: 2 nodes/wave, dual 8-deep SGPR-uniform gather streams ---
__device__ void phase_aggr(int NB, const unsigned* __restrict__ tbs,
        const unsigned* __restrict__ csr, const int* __restrict__ offs,
        const int* __restrict__ cnt, const float* __restrict__ dinv,
        const float* __restrict__ bnA, const float* __restrict__ bnB,
        unsigned* __restrict__ hout) {
    int t = threadIdx.x, wave = t >> 6, lane = t & 63;
    for (int cid = blockIdx.x; cid < NN / 32; cid += NB) {
        int n0 = cid * 32 + wave * 2;
        int n1 = n0 + 1;
        int base0 = __builtin_amdgcn_readfirstlane(offs[n0]);
        int base1 = __builtin_amdgcn_readfirstlane(offs[n1]);
        int ne0   = __builtin_amdgcn_readfirstlane(cnt[n0]);
        int ne1   = __builtin_amdgcn_readfirstlane(cnt[n1]);
        float dd0 = __uint_as_float(__builtin_amdgcn_readfirstlane(
                        (int)__float_as_uint(dinv[n0])));
        float dd1 = __uint_as_float(__builtin_amdgcn_readfirstlane(
                        (int)__float_as_uint(dinv[n1])));
        unsigned sv0 = tbs[(size_t)n0 * 64 + lane];
        unsigned sv1 = tbs[(size_t)n1 * 64 + lane];
        float ax0 = lo16(sv0), ay0 = hi16(sv0);
        float ax1 = lo16(sv1), ay1 = hi16(sv1);
        const unsigned* __restrict__ e0 = csr + base0;
        const unsigned* __restrict__ e1 = csr + base1;
        int nr0 = (ne0 + 7) & ~7, nr1 = (ne1 + 7) & ~7;
        int nr = nr0 > nr1 ? nr0 : nr1;
        for (int k0 = 0; k0 < nr; k0 += 8) {
            unsigned vv0[8], vv1[8];
            bool a0 = k0 < nr0, a1 = k0 < nr1;
            if (a0) {
#pragma unroll
                for (int j = 0; j < 8; j++) {
                    int s = (int)e0[k0 + j];
                    vv0[j] = tbs[(size_t)s * 64 + lane];
                }
            }
            if (a1) {
#pragma unroll
                for (int j = 0; j < 8; j++) {
                    int s = (int)e1[k0 + j];
                    vv1[j] = tbs[(size_t)s * 64 + lane];
                }
            }
            if (a0) {
#pragma unroll
                for (int j = 0; j < 8; j++) {
                    ax0 += lo16(vv0[j]);
                    ay0 += hi16(vv0[j]);
                }
            }
            if (a1) {
#pragma unroll
                for (int j = 0; j < 8; j++) {
                    ax1 += lo16(vv1[j]);
                    ay1 += hi16(vv1[j]);
                }
            }
        }
        float2 Av = ((const float2*)bnA)[lane];
        float2 Bv = ((const float2*)bnB)[lane];
        float r0 = fmaxf(fmaf(ax0 * dd0, Av.x, Bv.x), 0.f);
        float r1 = fmaxf(fmaf(ay0 * dd0, Av.y, Bv.y), 0.f);
        float r2 = fmaxf(fmaf(ax1 * dd1, Av.x, Bv.x), 0.f);
        float r3 = fmaxf(fmaf(ay1 * dd1, Av.y, Bv.y), 0.f);
        hout[(size_t)n0 * 64 + lane] = pack2(r0, r1);
        hout[(size_t)n1 * 64 + lane] = pack2(r2, r3);
    }
}

// ---- pool phase: one WAVE per 32-node chunk, run-flush atomics -----------
__device__ void phase_pool(int NB, int f, const unsigned* __restrict__ hb,
        const int* __restrict__ batch, float* __restrict__ gsum,
        float* __restrict__ gcnt) {
    int t = threadIdx.x, wave = t >> 6, lane = t & 63;
    for (int cid = blockIdx.x * 16 + wave; cid < NN / PN; cid += NB * 16) {
        int s0 = cid * PN;
        int cur = geti(batch, s0, f);
        float a0 = 0.f, a1 = 0.f, cn = 0.f;
        auto step = [&](int g, unsigned v) {
            if (g != cur) {                    // wave-uniform branch
                atomicAdd(&gsum[cur * HH + 2 * lane], a0);
                atomicAdd(&gsum[cur * HH + 2 * lane + 1], a1);
                if (lane == 0) atomicAdd(&gcnt[cur], cn);
                a0 = a1 = cn = 0.f; cur = g;
            }
            a0 += lo16(v); a1 += hi16(v); cn += 1.f;
        };
        for (int n = s0; n < s0 + PN; n += 8) {
            int gg[8]; unsigned vv[8];
#pragma unroll
            for (int j = 0; j < 8; j++) {
                gg[j] = geti(batch, n + j, f);
                vv[j] = hb[(size_t)(n + j) * 64 + lane];
            }
#pragma unroll
            for (int j = 0; j < 8; j++) step(gg[j], vv[j]);
        }
        atomicAdd(&gsum[cur * HH + 2 * lane], a0);
        atomicAdd(&gsum[cur * HH + 2 * lane + 1], a1);
        if (lane == 0) atomicAdd(&gcnt[cur], cn);
    }
}

// ---- ghead phase: blocks 0..63, w1 in LDS (pad 129) ----------------------
__device__ void phase_ghead(char* smem, const MegaArgs& A) {
    if (blockIdx.x >= GG) return;
    float* w1s = (float*)smem;                 // 64*129
    float* emb = (float*)(smem + 33024);       // 128
    int g = blockIdx.x, t = threadIdx.x;
    for (int gi = t; gi < 64 * HH; gi += 1024)
        w1s[(gi >> 7) * 129 + (gi & 127)] = A.gw1[gi];
    if (t < HH) {
        float cn = A.gcnt[g];
        cn = cn > 1.f ? cn : 1.f;
        emb[t] = A.gsum[g * HH + t] * (1.f / cn);
    }
    __syncthreads();
    if (t < 64) {
        float acc = A.gb1[t];
        for (int k = 0; k < HH; k++) acc = fmaf(emb[k], w1s[t * 129 + k], acc);
        float y = fmaxf(acc, 0.f);
        float v0 = y * A.gw2[t];
        float v1 = y * A.gw2[64 + t];
#pragma unroll
        for (int off = 32; off; off >>= 1) {
            v0 += __shfl_xor(v0, off);
            v1 += __shfl_xor(v1, off);
        }
        if (t == 0) {
            A.out[(size_t)NN * 2 + g * 2]     = v0 + A.gb2[0];
            A.out[(size_t)NN * 2 + g * 2 + 1] = v1 + A.gb2[1];
        }
    }
}

// ---- the mega kernel: whole pipeline, 9 grid syncs, 1 launch -------------
__global__ __launch_bounds__(1024, 8) void k_mega(MegaArgs A) {
    __shared__ __align__(16) char smem[SMEM_BYTES];
    cg::grid_group grid = cg::this_grid();
    int NB = (int)gridDim.x;
    int t = threadIdx.x;
    // int64 layout <=> odd int32 slots all zero over a 64-edge probe
    int probe = A.ei[2 * (t & 63) + 1];
    int f = __any(probe != 0) ? 0 : 1;
    phase_part(smem, NB, f, A);
    grid.sync();
    phase_csr(smem, NB, A);
    grid.sync();
    phase_gemm<float, HH, false>(smem, NB, A.x, A.cwB, nullptr, A.tb, 0,
                                 A.dinv, nullptr, nullptr, nullptr);
    grid.sync();
    phase_aggr(NB, (const unsigned*)A.tb, A.csr, A.offs, A.cnt, A.dinv,
               A.bnA, A.bnB, (unsigned*)A.hb);
    grid.sync();
    for (int l = 1; l < LL; l++) {
        phase_gemm<unsigned short, HH, false>(smem, NB, A.hb,
            A.cwB + (size_t)l * HH * HH, nullptr, A.tb, 0, A.dinv,
            nullptr, nullptr, nullptr);
        grid.sync();
        phase_aggr(NB, (const unsigned*)A.tb, A.csr, A.offs, A.cnt, A.dinv,
                   A.bnA + l * HH, A.bnB + l * HH, (unsigned*)A.hb);
        grid.sync();
    }
    // node head (FUSE) + pool partials in the same phase (independent)
    phase_gemm<unsigned short, 64, true>(smem, NB, A.hb, A.n1B, A.nb1,
        nullptr, 1, nullptr, A.nw2, A.nb2, A.out);
    phase_pool(NB, f, (const unsigned*)A.hb, A.batch, A.gsum, A.gcnt);
    grid.sync();
    phase_ghead(smem, A);
}

extern "C" void kernel_launch(void* const* d_in, const int* in_sizes, int n_in,
                              void* d_out, int out_size, void* d_ws, size_t ws_size,
                              hipStream_t stream) {
    MegaArgs ma;
    ma.ei     = (const int*)d_in[1];
    ma.batch  = (const int*)d_in[2];
    ma.x      = (const float*)d_in[0];
    ma.conv_w = (const float*)d_in[3];
    ma.conv_b = (const float*)d_in[4];
    ma.bn_g   = (const float*)d_in[5];
    ma.bn_b   = (const float*)d_in[6];
    ma.bn_m   = (const float*)d_in[7];
    ma.bn_v   = (const float*)d_in[8];
    ma.nw1    = (const float*)d_in[9];
    ma.nb1    = (const float*)d_in[10];
    ma.nw2    = (const float*)d_in[11];
    ma.nb2    = (const float*)d_in[12];
    ma.gw1    = (const float*)d_in[13];
    ma.gb1    = (const float*)d_in[14];
    ma.gw2    = (const float*)d_in[15];
    ma.gb2    = (const float*)d_in[16];
    ma.out    = (float*)d_out;

    char* ws = (char*)d_ws;
    size_t off = 0;
    auto alloc = [&](size_t bytes) -> void* {
        void* p = ws + off;
        off += (bytes + 255) & ~(size_t)255;
        return p;
    };
    ma.hb    = (unsigned short*)alloc((size_t)NN * HH * 2);
    ma.tb    = (unsigned short*)alloc((size_t)(NN + 1) * HH * 2);
    ma.chunk = (unsigned*)alloc((size_t)EE * 4);
    ma.csr   = (unsigned*)alloc((size_t)NT * CAP * 4);
    ma.lbu   = (unsigned short*)alloc((size_t)NT * CHW * 2);
    ma.offs  = (int*)alloc((size_t)NN * 4);
    ma.cnt   = (int*)alloc((size_t)NN * 4);
    ma.dinv  = (float*)alloc((size_t)NN * 4);
    ma.bnA   = (float*)alloc((size_t)LL * HH * 4);
    ma.bnB   = (float*)alloc((size_t)LL * HH * 4);
    ma.gsum  = (float*)alloc((size_t)GG * HH * 4);
    ma.gcnt  = (float*)alloc((size_t)GG * 4);
    ma.cwB   = (unsigned short*)alloc((size_t)LL * HH * HH * 2);
    ma.n1B   = (unsigned short*)alloc((size_t)64 * HH * 2);
    ma.flag  = (int*)alloc(256);

    int occ = 0;
    hipOccupancyMaxActiveBlocksPerMultiprocessor(&occ, k_mega, 1024, 0);
    if (occ < 1) occ = 1;
    if (occ > 2) occ = 2;
    int nb = occ * 256;
    void* kargs[] = { (void*)&ma };
    hipLaunchCooperativeKernel((void*)k_mega, dim3(nb), dim3(1024), kargs,
                               0, stream);
}

// Round 10
// 777.408 us; speedup vs baseline: 1.1453x; 1.1453x over previous
//
#include <hip/hip_runtime.h>
#include <hip/hip_bf16.h>
#include <hip/hip_cooperative_groups.h>

namespace cg = cooperative_groups;

#define NN 100000
#define EE 1600000
#define HH 128
#define GG 64
#define LL 3
#define BN_EPS 1e-5f
#define NT 391              // ceil(EE/4096) edge tiles == ceil(NN/256) node tiles
#define CHW 392             // lbu row width (NT+1)
#define CAP 6144            // per-tile csr slab capacity (pad-8)
#define PN 32               // pool chunk
#define NTG 391             // ceil(NN/256) row tiles for the 1024-thread gemm
#define SMEM_BYTES 55552

typedef __hip_bfloat16 bf16;
typedef __attribute__((ext_vector_type(8))) short short8;
typedef __attribute__((ext_vector_type(4))) float floatx4;

__device__ __forceinline__ float lo16(unsigned v) { return __uint_as_float(v << 16); }
__device__ __forceinline__ float hi16(unsigned v) { return __uint_as_float(v & 0xffff0000u); }
__device__ __forceinline__ unsigned short f2b(float v) {
    bf16 h = __float2bfloat16(v);
    return *(unsigned short*)&h;
}
__device__ __forceinline__ unsigned pack2(float a, float b) {
    return (unsigned)f2b(a) | ((unsigned)f2b(b) << 16);
}
__device__ __forceinline__ int geti(const int* __restrict__ p, int i, int f) {
    return f ? p[2 * i] : p[i];
}

struct MegaArgs {
    const int* ei; const int* batch; const float* x;
    const float* conv_w; const float* conv_b;
    const float* bn_g; const float* bn_b; const float* bn_m; const float* bn_v;
    const float* nw1; const float* nb1; const float* nw2; const float* nb2;
    const float* gw1; const float* gb1; const float* gw2; const float* gb2;
    float* out;
    unsigned short* hb; unsigned short* tb;
    unsigned* chunk; unsigned* csr; unsigned short* lbu;
    int* offs; int* cnt; float* dinv;
    float* bnA; float* bnB; float* gsum; float* gcnt;
    unsigned short* cwB; unsigned short* n1B; int* flag;
};

// ---- phase 1: prep + block-local edge tile sort (r8 k_part body) ---------
__device__ void phase_part(char* smem, int NB, int f, const MegaArgs& A) {
    int* lcnt = (int*)smem;                                // NT ints
    int* wsum = (int*)(smem + 1568);                       // 8
    unsigned short* lbs = (unsigned short*)(smem + 1600);  // CHW
    unsigned* sorted = (unsigned*)(smem + 2384);           // 4096
    int t = threadIdx.x;
    // one-shot prep, spread over the grid (NB*1024 >= 256K > all arrays)
    int gi = blockIdx.x * 1024 + t;
    if (gi < LL * HH * HH) A.cwB[gi] = f2b(A.conv_w[gi]);
    if (gi < 64 * HH) A.n1B[gi] = f2b(A.nw1[gi]);
    if (gi < LL * HH) {
        float Av = A.bn_g[gi] * rsqrtf(A.bn_v[gi] + BN_EPS);
        A.bnA[gi] = Av;
        A.bnB[gi] = (A.conv_b[gi] - A.bn_m[gi]) * Av + A.bn_b[gi];
    }
    if (gi < GG * HH) A.gsum[gi] = 0.f;
    if (gi < GG) A.gcnt[gi] = 0.f;
    if (gi < 64) ((unsigned*)A.tb)[(size_t)NN * 64 + gi] = 0u;  // zero pad-row
    if (blockIdx.x == 0 && t == 0) *A.flag = f;
    for (int T = blockIdx.x; T < NT; T += NB) {
        int e0 = T * 4096;
        int nume = EE - e0 < 4096 ? EE - e0 : 4096;
        for (int i = t; i < NT; i += 1024) lcnt[i] = 0;
        __syncthreads();
        unsigned pk[4]; int ml[4], mt[4];
#pragma unroll
        for (int i = 0; i < 4; i++) {
            int li = i * 1024 + t;
            if (li < nume) {
                int e = e0 + li;
                int src = geti(A.ei, e, f), dst = geti(A.ei, EE + e, f);
                mt[i] = dst >> 8;
                pk[i] = ((unsigned)src << 8) | (unsigned)(dst & 255);
                ml[i] = atomicAdd(&lcnt[mt[i]], 1);
            }
        }
        __syncthreads();
        int own = 0, x = 0;
        if (t < 512) { own = t < NT ? lcnt[t] : 0; x = own; }
#pragma unroll
        for (int off = 1; off < 64; off <<= 1) {
            int y = __shfl_up(x, off);
            if ((t & 63) >= off) x += y;
        }
        if (t < 512 && (t & 63) == 63) wsum[t >> 6] = x;
        __syncthreads();
        if (t < NT) {
            int pre = 0, w = t >> 6;
#pragma unroll
            for (int i = 0; i < 7; i++) if (i < w) pre += wsum[i];
            lbs[t] = (unsigned short)(pre + x - own);
        }
        if (t == 0) lbs[NT] = (unsigned short)nume;
        __syncthreads();
#pragma unroll
        for (int i = 0; i < 4; i++) {
            int li = i * 1024 + t;
            if (li < nume) sorted[(int)lbs[mt[i]] + ml[i]] = pk[i];
        }
        if (t < CHW) A.lbu[T * CHW + t] = lbs[t];
        __syncthreads();
        for (int idx = t; idx < nume; idx += 1024)
            A.chunk[e0 + idx] = sorted[idx];
    }
}

// ---- phase 2: per-tile CSR, 8-padded segments (r8 k_csr body) ------------
__device__ void phase_csr(char* smem, int NB, const MegaArgs& A) {
    unsigned* stage = (unsigned*)smem;                 // CAP
    unsigned* outb  = (unsigned*)(smem + 24576);       // CAP
    int* segso = (int*)(smem + 49152);                 // 512
    int* segst = (int*)(smem + 51200);                 // 512
    int* hist  = (int*)(smem + 53248);                 // 256
    int* cur   = (int*)(smem + 54272);                 // 256
    int* wsum  = (int*)(smem + 55296);                 // 8
    int* w2x   = (int*)(smem + 55328);                 // 4
    int* s_nep = (int*)(smem + 55344);                 // 1
    int t = threadIdx.x;
    for (int T = blockIdx.x; T < NT; T += NB) {
        int st = 0, rl = 0;
        if (t < NT) {
            int s0 = A.lbu[t * CHW + T];
            int s1 = A.lbu[t * CHW + T + 1];
            st = t * 4096 + s0;
            rl = s1 - s0;
        }
        int x = (t < 512) ? rl : 0;
#pragma unroll
        for (int off = 1; off < 64; off <<= 1) {
            int y = __shfl_up(x, off);
            if ((t & 63) >= off) x += y;
        }
        if (t < 512 && (t & 63) == 63) wsum[t >> 6] = x;
        if (t < 256) hist[t] = 0;
        __syncthreads();
        int tot = 0;
#pragma unroll
        for (int i = 0; i < 8; i++) tot += wsum[i];
        int ne = tot > CAP ? CAP : tot;
        if (t < 512) {
            int pre = 0, w = t >> 6;
#pragma unroll
            for (int i = 0; i < 7; i++) if (i < w) pre += wsum[i];
            segso[t] = pre + x - rl;
            segst[t] = st;
        }
        __syncthreads();
        for (int i = t; i < ne; i += 1024) {
            int lo = 0;
#pragma unroll
            for (int b = 256; b; b >>= 1) {
                int nlo = lo + b;
                if (nlo < 512 && segso[nlo] <= i) lo = nlo;
            }
            stage[i] = A.chunk[segst[lo] + (i - segso[lo])];
        }
        __syncthreads();
        for (int i = t; i < ne; i += 1024)
            atomicAdd(&hist[stage[i] & 255u], 1);
        __syncthreads();
        int c = 0, pc = 0, x2 = 0;
        if (t < 256) {
            c = hist[t];
            pc = (c + 7) & ~7;
            x2 = pc;
        }
#pragma unroll
        for (int off = 1; off < 64; off <<= 1) {
            int y = __shfl_up(x2, off);
            if ((t & 63) >= off) x2 += y;
        }
        if (t < 256 && (t & 63) == 63) w2x[t >> 6] = x2;
        __syncthreads();
        if (t < 256) {
            int pre = 0, w = t >> 6;
#pragma unroll
            for (int i = 0; i < 3; i++) if (i < w) pre += w2x[i];
            int stn = pre + x2 - pc;
            cur[t] = stn;
            int node = T * 256 + t;
            if (node < NN) {
                A.offs[node] = T * CAP + stn;
                A.cnt[node] = c;
                A.dinv[node] = rsqrtf(1.0f + (float)c);
            }
            for (int i = stn + c; i < stn + pc && i < CAP; i++)
                outb[i] = NN;
        }
        if (t == 0) {
            int tt = w2x[0] + w2x[1] + w2x[2] + w2x[3];
            *s_nep = tt < CAP ? tt : CAP;
        }
        __syncthreads();
        for (int i = t; i < ne; i += 1024) {
            unsigned p = stage[i];
            int q = atomicAdd(&cur[p & 255u], 1);
            if (q < CAP) outb[q] = p >> 8;
        }
        __syncthreads();
        int nep = *s_nep;
        for (int i = t; i < nep; i += 1024)
            A.csr[(size_t)T * CAP + i] = outb[i];
        __syncthreads();
    }
}

// ---- gemm phase: 1024 threads, 256-row tiles, W staged ONCE per phase ----
template<typename AT, int NC, bool FUSE>
__device__ void phase_gemm(char* smem, int NB, const AT* __restrict__ in,
        const unsigned short* __restrict__ Wb, const float* __restrict__ bias,
        unsigned short* __restrict__ outh, int do_relu,
        const float* __restrict__ scale, const float* __restrict__ w2,
        const float* __restrict__ b2v, float* __restrict__ out2f) {
    char* sB = smem;
    int t = threadIdx.x;
    int wave = t >> 6, lane = t & 63, ln = lane & 15, q = lane >> 4;
    const short8* wsrc = (const short8*)Wb;
    for (int i = t; i < NC * 16; i += 1024)
        *(short8*)(sB + (i >> 4) * 272 + (i & 15) * 16) = wsrc[i];
    __syncthreads();
    for (int T = blockIdx.x; T < NTG; T += NB) {
        int r0 = T * 256 + wave * 16;
        int row = r0 + ln;
        int rr = row < NN ? row : NN - 1;
        short8 a[4];
        if constexpr (sizeof(AT) == 2) {
            const short8* ap = (const short8*)(in + (size_t)rr * HH);
#pragma unroll
            for (int kt = 0; kt < 4; kt++) a[kt] = ap[kt * 4 + q];
        } else {
            const float4* ap = (const float4*)(in + (size_t)rr * HH);
#pragma unroll
            for (int kt = 0; kt < 4; kt++) {
                float4 f0 = ap[(kt * 4 + q) * 2];
                float4 f1 = ap[(kt * 4 + q) * 2 + 1];
                a[kt][0] = (short)f2b(f0.x); a[kt][1] = (short)f2b(f0.y);
                a[kt][2] = (short)f2b(f0.z); a[kt][3] = (short)f2b(f0.w);
                a[kt][4] = (short)f2b(f1.x); a[kt][5] = (short)f2b(f1.y);
                a[kt][6] = (short)f2b(f1.z); a[kt][7] = (short)f2b(f1.w);
            }
        }
        float scl[4];
        if constexpr (!FUSE) {
#pragma unroll
            for (int reg = 0; reg < 4; reg++) {
                int orow = r0 + q * 4 + reg;
                scl[reg] = scale ? scale[orow < NN ? orow : NN - 1] : 1.f;
            }
        }
        float p0[4], p1[4];
        if constexpr (FUSE) {
#pragma unroll
            for (int r = 0; r < 4; r++) { p0[r] = 0.f; p1[r] = 0.f; }
        }
#pragma unroll
        for (int ct = 0; ct < NC / 16; ct++) {
            int c = ct * 16 + ln;
            floatx4 acc = {0.f, 0.f, 0.f, 0.f};
#pragma unroll
            for (int kt = 0; kt < 4; kt++) {
                short8 b = *(const short8*)(sB + (size_t)c * 272 + kt * 64 + q * 16);
                acc = __builtin_amdgcn_mfma_f32_16x16x32_bf16(a[kt], b, acc, 0, 0, 0);
            }
            float bv = bias ? bias[c] : 0.f;
            if constexpr (FUSE) {
                float wa = w2[c], wb = w2[64 + c];
#pragma unroll
                for (int reg = 0; reg < 4; reg++) {
                    float v = fmaxf(acc[reg] + bv, 0.f);
                    p0[reg] = fmaf(v, wa, p0[reg]);
                    p1[reg] = fmaf(v, wb, p1[reg]);
                }
            } else {
#pragma unroll
                for (int reg = 0; reg < 4; reg++) {
                    int orow = r0 + q * 4 + reg;   // C/D: col=lane&15, row=quad*4+reg
                    if (orow < NN) {
                        float v = acc[reg] + bv;
                        if (do_relu) v = fmaxf(v, 0.f);
                        outh[(size_t)orow * NC + c] = f2b(v * scl[reg]);
                    }
                }
            }
        }
        if constexpr (FUSE) {
#pragma unroll
            for (int off = 1; off < 16; off <<= 1) {
#pragma unroll
                for (int r = 0; r < 4; r++) {
                    p0[r] += __shfl_xor(p0[r], off);
                    p1[r] += __shfl_xor(p1[r], off);
                }
            }
            if (ln == 0) {
                float ba = b2v[0], bb = b2v[1];
#pragma unroll
                for (int reg = 0; reg < 4; reg++) {
                    int orow = r0 + q * 4 + reg;
                    if (orow < NN)
                        ((float2*)out2f)[orow] = make_float2(p0[reg] + ba, p1[reg] + bb);
                }
            }
        }
    }
}

// ---- aggr phase: 2 nodes/wave, dual 8-deep SGPR-uniform gather streams ---
__device__ void phase_aggr(int NB, const unsigned* __restrict__ tbs,
        const unsigned* __restrict__ csr, const int* __restrict__ offs,
        const int* __restrict__ cnt, const float* __restrict__ dinv,
        const float* __restrict__ bnA, const float* __restrict__ bnB,
        unsigned* __restrict__ hout) {
    int t = threadIdx.x, wave = t >> 6, lane = t & 63;
    for (int cid = blockIdx.x; cid < NN / 32; cid += NB) {
        int n0 = cid * 32 + wave * 2;
        int n1 = n0 + 1;
        int base0 = __builtin_amdgcn_readfirstlane(offs[n0]);
        int base1 = __builtin_amdgcn_readfirstlane(offs[n1]);
        int ne0   = __builtin_amdgcn_readfirstlane(cnt[n0]);
        int ne1   = __builtin_amdgcn_readfirstlane(cnt[n1]);
        float dd0 = __uint_as_float(__builtin_amdgcn_readfirstlane(
                        (int)__float_as_uint(dinv[n0])));
        float dd1 = __uint_as_float(__builtin_amdgcn_readfirstlane(
                        (int)__float_as_uint(dinv[n1])));
        unsigned sv0 = tbs[(size_t)n0 * 64 + lane];
        unsigned sv1 = tbs[(size_t)n1 * 64 + lane];
        float ax0 = lo16(sv0), ay0 = hi16(sv0);
        float ax1 = lo16(sv1), ay1 = hi16(sv1);
        const unsigned* __restrict__ e0 = csr + base0;
        const unsigned* __restrict__ e1 = csr + base1;
        int nr0 = (ne0 + 7) & ~7, nr1 = (ne1 + 7) & ~7;
        int nr = nr0 > nr1 ? nr0 : nr1;
        for (int k0 = 0; k0 < nr; k0 += 8) {
            unsigned vv0[8], vv1[8];
            bool a0 = k0 < nr0, a1 = k0 < nr1;
            if (a0) {
#pragma unroll
                for (int j = 0; j < 8; j++) {
                    int s = (int)e0[k0 + j];
                    vv0[j] = tbs[(size_t)s * 64 + lane];
                }
            }
            if (a1) {
#pragma unroll
                for (int j = 0; j < 8; j++) {
                    int s = (int)e1[k0 + j];
                    vv1[j] = tbs[(size_t)s * 64 + lane];
                }
            }
            if (a0) {
#pragma unroll
                for (int j = 0; j < 8; j++) {
                    ax0 += lo16(vv0[j]);
                    ay0 += hi16(vv0[j]);
                }
            }
            if (a1) {
#pragma unroll
                for (int j = 0; j < 8; j++) {
                    ax1 += lo16(vv1[j]);
                    ay1 += hi16(vv1[j]);
                }
            }
        }
        float2 Av = ((const float2*)bnA)[lane];
        float2 Bv = ((const float2*)bnB)[lane];
        float r0 = fmaxf(fmaf(ax0 * dd0, Av.x, Bv.x), 0.f);
        float r1 = fmaxf(fmaf(ay0 * dd0, Av.y, Bv.y), 0.f);
        float r2 = fmaxf(fmaf(ax1 * dd1, Av.x, Bv.x), 0.f);
        float r3 = fmaxf(fmaf(ay1 * dd1, Av.y, Bv.y), 0.f);
        hout[(size_t)n0 * 64 + lane] = pack2(r0, r1);
        hout[(size_t)n1 * 64 + lane] = pack2(r2, r3);
    }
}

// ---- pool phase: one WAVE per 32-node chunk, run-flush atomics -----------
__device__ void phase_pool(int NB, int f, const unsigned* __restrict__ hb,
        const int* __restrict__ batch, float* __restrict__ gsum,
        float* __restrict__ gcnt) {
    int t = threadIdx.x, wave = t >> 6, lane = t & 63;
    for (int cid = blockIdx.x * 16 + wave; cid < NN / PN; cid += NB * 16) {
        int s0 = cid * PN;
        int cur = geti(batch, s0, f);
        float a0 = 0.f, a1 = 0.f, cn = 0.f;
        auto step = [&](int g, unsigned v) {
            if (g != cur) {                    // wave-uniform branch
                atomicAdd(&gsum[cur * HH + 2 * lane], a0);
                atomicAdd(&gsum[cur * HH + 2 * lane + 1], a1);
                if (lane == 0) atomicAdd(&gcnt[cur], cn);
                a0 = a1 = cn = 0.f; cur = g;
            }
            a0 += lo16(v); a1 += hi16(v); cn += 1.f;
        };
        for (int n = s0; n < s0 + PN; n += 8) {
            int gg[8]; unsigned vv[8];
#pragma unroll
            for (int j = 0; j < 8; j++) {
                gg[j] = geti(batch, n + j, f);
                vv[j] = hb[(size_t)(n + j) * 64 + lane];
            }
#pragma unroll
            for (int j = 0; j < 8; j++) step(gg[j], vv[j]);
        }
        atomicAdd(&gsum[cur * HH + 2 * lane], a0);
        atomicAdd(&gsum[cur * HH + 2 * lane + 1], a1);
        if (lane == 0) atomicAdd(&gcnt[cur], cn);
    }
}

// ---- ghead phase: blocks 0..63, w1 in LDS (pad 129) ----------------------
__device__ void phase_ghead(char* smem, const MegaArgs& A) {
    if (blockIdx.x >= GG) return;
    float* w1s = (float*)smem;                 // 64*129
    float* emb = (float*)(smem + 33024);       // 128
    int g = blockIdx.x, t = threadIdx.x;
    for (int gi = t; gi < 64 * HH; gi += 1024)
        w1s[(gi >> 7) * 129 + (gi & 127)] = A.gw1[gi];
    if (t < HH) {
        float cn = A.gcnt[g];
        cn = cn > 1.f ? cn : 1.f;
        emb[t] = A.gsum[g * HH + t] * (1.f / cn);
    }
    __syncthreads();
    if (t < 64) {
        float acc = A.gb1[t];
        for (int k = 0; k < HH; k++) acc = fmaf(emb[k], w1s[t * 129 + k], acc);
        float y = fmaxf(acc, 0.f);
        float v0 = y * A.gw2[t];
        float v1 = y * A.gw2[64 + t];
#pragma unroll
        for (int off = 32; off; off >>= 1) {
            v0 += __shfl_xor(v0, off);
            v1 += __shfl_xor(v1, off);
        }
        if (t == 0) {
            A.out[(size_t)NN * 2 + g * 2]     = v0 + A.gb2[0];
            A.out[(size_t)NN * 2 + g * 2 + 1] = v1 + A.gb2[1];
        }
    }
}

// ---- the mega kernel: whole pipeline, 9 grid syncs, 1 launch -------------
// r10: min-waves/EU 8 -> 4 (VGPR cap 64 -> 128). r9's cap forced scratch
// spills (VGPR=32 reported, +1GB spill traffic, VALUBusy 9.7%).
__global__ __launch_bounds__(1024, 4) void k_mega(MegaArgs A) {
    __shared__ __align__(16) char smem[SMEM_BYTES];
    cg::grid_group grid = cg::this_grid();
    int NB = (int)gridDim.x;
    int t = threadIdx.x;
    // int64 layout <=> odd int32 slots all zero over a 64-edge probe
    int probe = A.ei[2 * (t & 63) + 1];
    int f = __any(probe != 0) ? 0 : 1;
    phase_part(smem, NB, f, A);
    grid.sync();
    phase_csr(smem, NB, A);
    grid.sync();
    phase_gemm<float, HH, false>(smem, NB, A.x, A.cwB, nullptr, A.tb, 0,
                                 A.dinv, nullptr, nullptr, nullptr);
    grid.sync();
    phase_aggr(NB, (const unsigned*)A.tb, A.csr, A.offs, A.cnt, A.dinv,
               A.bnA, A.bnB, (unsigned*)A.hb);
    grid.sync();
    for (int l = 1; l < LL; l++) {
        phase_gemm<unsigned short, HH, false>(smem, NB, A.hb,
            A.cwB + (size_t)l * HH * HH, nullptr, A.tb, 0, A.dinv,
            nullptr, nullptr, nullptr);
        grid.sync();
        phase_aggr(NB, (const unsigned*)A.tb, A.csr, A.offs, A.cnt, A.dinv,
                   A.bnA + l * HH, A.bnB + l * HH, (unsigned*)A.hb);
        grid.sync();
    }
    // node head (FUSE) + pool partials in the same phase (independent)
    phase_gemm<unsigned short, 64, true>(smem, NB, A.hb, A.n1B, A.nb1,
        nullptr, 1, nullptr, A.nw2, A.nb2, A.out);
    phase_pool(NB, f, (const unsigned*)A.hb, A.batch, A.gsum, A.gcnt);
    grid.sync();
    phase_ghead(smem, A);
}

extern "C" void kernel_launch(void* const* d_in, const int* in_sizes, int n_in,
                              void* d_out, int out_size, void* d_ws, size_t ws_size,
                              hipStream_t stream) {
    MegaArgs ma;
    ma.ei     = (const int*)d_in[1];
    ma.batch  = (const int*)d_in[2];
    ma.x      = (const float*)d_in[0];
    ma.conv_w = (const float*)d_in[3];
    ma.conv_b = (const float*)d_in[4];
    ma.bn_g   = (const float*)d_in[5];
    ma.bn_b   = (const float*)d_in[6];
    ma.bn_m   = (const float*)d_in[7];
    ma.bn_v   = (const float*)d_in[8];
    ma.nw1    = (const float*)d_in[9];
    ma.nb1    = (const float*)d_in[10];
    ma.nw2    = (const float*)d_in[11];
    ma.nb2    = (const float*)d_in[12];
    ma.gw1    = (const float*)d_in[13];
    ma.gb1    = (const float*)d_in[14];
    ma.gw2    = (const float*)d_in[15];
    ma.gb2    = (const float*)d_in[16];
    ma.out    = (float*)d_out;

    char* ws = (char*)d_ws;
    size_t off = 0;
    auto alloc = [&](size_t bytes) -> void* {
        void* p = ws + off;
        off += (bytes + 255) & ~(size_t)255;
        return p;
    };
    ma.hb    = (unsigned short*)alloc((size_t)NN * HH * 2);
    ma.tb    = (unsigned short*)alloc((size_t)(NN + 1) * HH * 2);
    ma.chunk = (unsigned*)alloc((size_t)EE * 4);
    ma.csr   = (unsigned*)alloc((size_t)NT * CAP * 4);
    ma.lbu   = (unsigned short*)alloc((size_t)NT * CHW * 2);
    ma.offs  = (int*)alloc((size_t)NN * 4);
    ma.cnt   = (int*)alloc((size_t)NN * 4);
    ma.dinv  = (float*)alloc((size_t)NN * 4);
    ma.bnA   = (float*)alloc((size_t)LL * HH * 4);
    ma.bnB   = (float*)alloc((size_t)LL * HH * 4);
    ma.gsum  = (float*)alloc((size_t)GG * HH * 4);
    ma.gcnt  = (float*)alloc((size_t)GG * 4);
    ma.cwB   = (unsigned short*)alloc((size_t)LL * HH * HH * 2);
    ma.n1B   = (unsigned short*)alloc((size_t)64 * HH * 2);
    ma.flag  = (int*)alloc(256);

    int occ = 0;
    hipOccupancyMaxActiveBlocksPerMultiprocessor(&occ, k_mega, 1024, 0);
    if (occ < 1) occ = 1;
    if (occ > 2) occ = 2;
    int nb = occ * 256;
    void* kargs[] = { (void*)&ma };
    hipLaunchCooperativeKernel((void*)k_mega, dim3(nb), dim3(1024), kargs,
                               0, stream);
}

// Round 11
// 409.360 us; speedup vs baseline: 2.1750x; 1.8991x over previous
//
#include <hip/hip_runtime.h>
#include <hip/hip_bf16.h>

#define NN 100000
#define EE 1600000
#define HH 128
#define GG 64
#define LL 3
#define BN_EPS 1e-5f
#define NT 391              // ceil(NN/256): 256-node tiles; also ceil(EE/4096)
#define CHW 392             // lbu row width (NT+1)
#define CAP 6144            // per-tile csr slab capacity (pad-8 mean ~5.1K, 13 sigma)

typedef __hip_bfloat16 bf16;
typedef __attribute__((ext_vector_type(8))) short short8;
typedef __attribute__((ext_vector_type(4))) float floatx4;

__device__ __forceinline__ float lo16(unsigned v) { return __uint_as_float(v << 16); }
__device__ __forceinline__ float hi16(unsigned v) { return __uint_as_float(v & 0xffff0000u); }
__device__ __forceinline__ unsigned short f2b(float v) {
    bf16 h = __float2bfloat16(v);
    return *(unsigned short*)&h;
}
__device__ __forceinline__ unsigned pack2(float a, float b) {
    return (unsigned)f2b(a) | ((unsigned)f2b(b) << 16);
}
__device__ __forceinline__ int geti(const int* __restrict__ p, int i, int f) {
    return f ? p[2 * i] : p[i];
}

// ---- pass 1: block-local tile sort, COALESCED chunk flush (no atomics) ---
// 512-wide scan via shfl wave-scan (2 barriers instead of 18).
__global__ __launch_bounds__(1024) void k_part(const int* __restrict__ ei,
        unsigned* __restrict__ chunk, unsigned short* __restrict__ lbu,
        int* __restrict__ flag,
        const float* __restrict__ conv_w, const float* __restrict__ nw1,
        unsigned short* __restrict__ cwB, unsigned short* __restrict__ n1B,
        float* __restrict__ bnA, float* __restrict__ bnB,
        const float* __restrict__ conv_b, const float* __restrict__ g,
        const float* __restrict__ be, const float* __restrict__ mn,
        const float* __restrict__ vr, float* __restrict__ gsum,
        float* __restrict__ gcnt, unsigned* __restrict__ tbz) {
    __shared__ int lcnt[NT];
    __shared__ int wsum[8];
    __shared__ unsigned short lbs[CHW];
    __shared__ unsigned sorted[4096];
    int t = threadIdx.x;
    int e0 = blockIdx.x * 4096;
    // int64 layout <=> odd int32 slots all zero over a 64-edge probe
    int probe = ei[2 * (e0 + (t & 63)) + 1];
    int f = __any(probe != 0) ? 0 : 1;
    if (blockIdx.x == 0 && t == 0) *flag = f;
    // one-shot prep, spread across the grid (grid covers 400K > all arrays)
    int gi = blockIdx.x * 1024 + t;
    if (gi < LL * HH * HH) cwB[gi] = f2b(conv_w[gi]);
    if (gi < 64 * HH) n1B[gi] = f2b(nw1[gi]);
    if (gi < LL * HH) {
        float A = g[gi] * rsqrtf(vr[gi] + BN_EPS);
        bnA[gi] = A;
        bnB[gi] = (conv_b[gi] - mn[gi]) * A + be[gi];
    }
    if (gi < GG * HH) gsum[gi] = 0.f;
    if (gi < GG) gcnt[gi] = 0.f;
    if (gi < 64) tbz[(size_t)NN * 64 + gi] = 0u;   // zero pad-row for gathers
    int nume = EE - e0 < 4096 ? EE - e0 : 4096;
    for (int i = t; i < NT; i += 1024) lcnt[i] = 0;
    __syncthreads();
    unsigned pk[4]; int ml[4], mt[4];
#pragma unroll
    for (int i = 0; i < 4; i++) {
        int li = i * 1024 + t;
        if (li < nume) {
            int e = e0 + li;
            int src = geti(ei, e, f), dst = geti(ei, EE + e, f);
            mt[i] = dst >> 8;
            pk[i] = ((unsigned)src << 8) | (unsigned)(dst & 255);
            ml[i] = atomicAdd(&lcnt[mt[i]], 1);
        }
    }
    __syncthreads();
    // shfl wave-scan of lcnt over 512 slots
    int own = 0, x = 0;
    if (t < 512) { own = t < NT ? lcnt[t] : 0; x = own; }
#pragma unroll
    for (int off = 1; off < 64; off <<= 1) {
        int y = __shfl_up(x, off);
        if ((t & 63) >= off) x += y;
    }
    if (t < 512 && (t & 63) == 63) wsum[t >> 6] = x;
    __syncthreads();
    if (t < NT) {
        int pre = 0, w = t >> 6;
#pragma unroll
        for (int i = 0; i < 7; i++) if (i < w) pre += wsum[i];
        lbs[t] = (unsigned short)(pre + x - own);
    }
    if (t == 0) lbs[NT] = (unsigned short)nume;
    __syncthreads();
#pragma unroll
    for (int i = 0; i < 4; i++) {
        int li = i * 1024 + t;
        if (li < nume) sorted[(int)lbs[mt[i]] + ml[i]] = pk[i];
    }
    if (t < CHW) lbu[blockIdx.x * CHW + t] = lbs[t];
    __syncthreads();
    for (int idx = t; idx < nume; idx += 1024)
        chunk[e0 + idx] = sorted[idx];         // plain store: keep cached
}

// ---- pass 2: per-tile CSR; 256-bin counting sort; 8-PADDED node segments -
// scans via shfl wave-scan (4 barriers); stage load parallel + coalesced
// via branchless binary search on the segment prefix.
__global__ __launch_bounds__(1024) void k_csr(const unsigned* __restrict__ chunk,
        const unsigned short* __restrict__ lbu, unsigned* __restrict__ csr,
        int* __restrict__ offs, int* __restrict__ cnt, float* __restrict__ dinv) {
    __shared__ unsigned stage[CAP];
    __shared__ unsigned outb[CAP];
    __shared__ int wsum[8];
    __shared__ int w2[4];
    __shared__ int segso[512];
    __shared__ int segst[512];
    __shared__ int hist[256], cur[256];
    __shared__ int s_nep;
    int T = blockIdx.x, t = threadIdx.x;
    int st = 0, rl = 0;
    if (t < NT) {
        int s0 = lbu[t * CHW + T];
        int s1 = lbu[t * CHW + T + 1];
        st = t * 4096 + s0;
        rl = s1 - s0;
    }
    // shfl wave-scan over 512 segment lengths
    int x = (t < 512) ? rl : 0;
#pragma unroll
    for (int off = 1; off < 64; off <<= 1) {
        int y = __shfl_up(x, off);
        if ((t & 63) >= off) x += y;
    }
    if (t < 512 && (t & 63) == 63) wsum[t >> 6] = x;
    if (t < 256) hist[t] = 0;
    __syncthreads();
    int tot = 0;
#pragma unroll
    for (int i = 0; i < 8; i++) tot += wsum[i];
    int ne = tot > CAP ? CAP : tot;            // never capped in practice
    if (t < 512) {
        int pre = 0, w = t >> 6;
#pragma unroll
        for (int i = 0; i < 7; i++) if (i < w) pre += wsum[i];
        segso[t] = pre + x - rl;               // exclusive prefix (sentinel tot)
        segst[t] = st;
    }
    __syncthreads();
    // parallel coalesced stage: element i -> largest seg with so[seg] <= i
    for (int i = t; i < ne; i += 1024) {
        int lo = 0;
#pragma unroll
        for (int b = 256; b; b >>= 1) {
            int nlo = lo + b;
            if (nlo < 512 && segso[nlo] <= i) lo = nlo;
        }
        stage[i] = chunk[segst[lo] + (i - segso[lo])];
    }
    __syncthreads();
    for (int i = t; i < ne; i += 1024)
        atomicAdd(&hist[stage[i] & 255u], 1);
    __syncthreads();
    // shfl wave-scan over 256 padded counts
    int c = 0, pc = 0, x2 = 0;
    if (t < 256) {
        c = hist[t];
        pc = (c + 7) & ~7;                     // pad each node to 8
        x2 = pc;
    }
#pragma unroll
    for (int off = 1; off < 64; off <<= 1) {
        int y = __shfl_up(x2, off);
        if ((t & 63) >= off) x2 += y;
    }
    if (t < 256 && (t & 63) == 63) w2[t >> 6] = x2;
    __syncthreads();
    if (t < 256) {
        int pre = 0, w = t >> 6;
#pragma unroll
        for (int i = 0; i < 3; i++) if (i < w) pre += w2[i];
        int stn = pre + x2 - pc;               // padded exclusive prefix
        cur[t] = stn;
        int node = T * 256 + t;
        if (node < NN) {
            offs[node] = T * CAP + stn;
            cnt[node] = c;
            dinv[node] = rsqrtf(1.0f + (float)c);
        }
        for (int i = stn + c; i < stn + pc && i < CAP; i++)
            outb[i] = NN;                      // pads -> zero row
    }
    if (t == 0) {
        int tt = w2[0] + w2[1] + w2[2] + w2[3];
        s_nep = tt < CAP ? tt : CAP;
    }
    __syncthreads();
    for (int i = t; i < ne; i += 1024) {
        unsigned p = stage[i];
        int q = atomicAdd(&cur[p & 255u], 1);
        if (q < CAP) outb[q] = p >> 8;         // pure src
    }
    __syncthreads();
    int nep = s_nep;
    for (int i = t; i < nep; i += 1024)
        csr[(size_t)T * CAP + i] = outb[i];
}

// ---- MFMA bf16 GEMM: out[r][c] = sum_k in[r][k]*W[c][k] (+bias, relu) ----
// W staged once per block into LDS (272B row stride: conflict-free b128).
// scale: per-ROW output scale (dinv prescale for the aggregation gather).
// FUSE: fold y2 = y1 @ w2^T + b2 (64->2) into the epilogue (node head).
template<typename AT, int NC, bool FUSE>
__global__ __launch_bounds__(256) void k_gemm(const AT* __restrict__ in,
        const unsigned short* __restrict__ Wb, const float* __restrict__ bias,
        unsigned short* __restrict__ outh, int do_relu,
        const float* __restrict__ scale,
        const float* __restrict__ w2, const float* __restrict__ b2v,
        float* __restrict__ out2f) {
    __shared__ char sB[NC * 272];
    int wave = threadIdx.x >> 6, lane = threadIdx.x & 63;
    int ln = lane & 15, q = lane >> 4;
    // stage W -> LDS (one-time; 16B chunks, padded rows)
    {
        const short8* wsrc = (const short8*)Wb;
        for (int i = threadIdx.x; i < NC * 16; i += 256) {
            short8 v = wsrc[i];
            *(short8*)(sB + (i >> 4) * 272 + (i & 15) * 16) = v;
        }
    }
    int r0 = blockIdx.x * 64 + wave * 16;
    int row = r0 + ln;
    int rr = row < NN ? row : NN - 1;          // clamp loads, guard stores
    short8 a[4];
    if constexpr (sizeof(AT) == 2) {
        const short8* ap = (const short8*)(in + (size_t)rr * HH);
#pragma unroll
        for (int kt = 0; kt < 4; kt++) a[kt] = ap[kt * 4 + q];
    } else {
        const float4* ap = (const float4*)(in + (size_t)rr * HH);
#pragma unroll
        for (int kt = 0; kt < 4; kt++) {
            float4 f0 = ap[(kt * 4 + q) * 2];
            float4 f1 = ap[(kt * 4 + q) * 2 + 1];
            a[kt][0] = (short)f2b(f0.x); a[kt][1] = (short)f2b(f0.y);
            a[kt][2] = (short)f2b(f0.z); a[kt][3] = (short)f2b(f0.w);
            a[kt][4] = (short)f2b(f1.x); a[kt][5] = (short)f2b(f1.y);
            a[kt][6] = (short)f2b(f1.z); a[kt][7] = (short)f2b(f1.w);
        }
    }
    float scl[4];
    if constexpr (!FUSE) {
#pragma unroll
        for (int reg = 0; reg < 4; reg++) {
            int orow = r0 + q * 4 + reg;
            scl[reg] = scale ? scale[orow < NN ? orow : NN - 1] : 1.f;
        }
    }
    __syncthreads();
    float p0[4], p1[4];
    if constexpr (FUSE) {
#pragma unroll
        for (int r = 0; r < 4; r++) { p0[r] = 0.f; p1[r] = 0.f; }
    }
#pragma unroll
    for (int ct = 0; ct < NC / 16; ct++) {
        int c = ct * 16 + ln;
        floatx4 acc = {0.f, 0.f, 0.f, 0.f};
#pragma unroll
        for (int kt = 0; kt < 4; kt++) {
            short8 b = *(const short8*)(sB + (size_t)c * 272 + kt * 64 + q * 16);
            acc = __builtin_amdgcn_mfma_f32_16x16x32_bf16(a[kt], b, acc, 0, 0, 0);
        }
        float bv = bias ? bias[c] : 0.f;
        if constexpr (FUSE) {
            float wa = w2[c], wb = w2[64 + c];
#pragma unroll
            for (int reg = 0; reg < 4; reg++) {
                float v = fmaxf(acc[reg] + bv, 0.f);   // y1 with bias+relu
                p0[reg] = fmaf(v, wa, p0[reg]);
                p1[reg] = fmaf(v, wb, p1[reg]);
            }
        } else {
#pragma unroll
            for (int reg = 0; reg < 4; reg++) {
                int orow = r0 + q * 4 + reg;   // C/D: col=lane&15, row=quad*4+reg
                if (orow < NN) {
                    float v = acc[reg] + bv;
                    if (do_relu) v = fmaxf(v, 0.f);
                    outh[(size_t)orow * NC + c] = f2b(v * scl[reg]);
                }
            }
        }
    }
    if constexpr (FUSE) {
#pragma unroll
        for (int off = 1; off < 16; off <<= 1) {
#pragma unroll
            for (int r = 0; r < 4; r++) {
                p0[r] += __shfl_xor(p0[r], off);
                p1[r] += __shfl_xor(p1[r], off);
            }
        }
        if (ln == 0) {
            float ba = b2v[0], bb = b2v[1];
#pragma unroll
            for (int reg = 0; reg < 4; reg++) {
                int orow = r0 + q * 4 + reg;
                if (orow < NN)
                    ((float2*)out2f)[orow] = make_float2(p0[reg] + ba, p1[reg] + bb);
            }
        }
    }
}

// ---- fused gather segment-reduce + self-loop + BN + ReLU -----------------
// TWO nodes per wave: two independent 8-deep gather streams -> 16 rows in
// flight per wave. edge indices are wave-uniform scalar loads (SGPR); t
// rows are dinv-prescaled by the GEMM epilogue; segments padded to 8.
// PLAIN hout stores (hb re-read immediately by next kernel -> keep hot).
__global__ __launch_bounds__(256) void k_aggr(const unsigned* __restrict__ tbs,
        const unsigned* __restrict__ csr, const int* __restrict__ offs,
        const int* __restrict__ cnt, const float* __restrict__ dinv,
        const float* __restrict__ bnA, const float* __restrict__ bnB,
        unsigned* __restrict__ hout) {
    int wave = threadIdx.x >> 6, lane = threadIdx.x & 63;
    int n0 = blockIdx.x * 8 + wave * 2;        // grid = NN/8 exactly
    int n1 = n0 + 1;
    int base0 = __builtin_amdgcn_readfirstlane(offs[n0]);
    int base1 = __builtin_amdgcn_readfirstlane(offs[n1]);
    int ne0   = __builtin_amdgcn_readfirstlane(cnt[n0]);
    int ne1   = __builtin_amdgcn_readfirstlane(cnt[n1]);
    float dd0 = __uint_as_float(__builtin_amdgcn_readfirstlane(
                    (int)__float_as_uint(dinv[n0])));
    float dd1 = __uint_as_float(__builtin_amdgcn_readfirstlane(
                    (int)__float_as_uint(dinv[n1])));
    unsigned sv0 = tbs[(size_t)n0 * 64 + lane];    // self (prescaled)
    unsigned sv1 = tbs[(size_t)n1 * 64 + lane];
    float ax0 = lo16(sv0), ay0 = hi16(sv0);
    float ax1 = lo16(sv1), ay1 = hi16(sv1);
    const unsigned* __restrict__ e0 = csr + base0;
    const unsigned* __restrict__ e1 = csr + base1;
    int nr0 = (ne0 + 7) & ~7, nr1 = (ne1 + 7) & ~7;
    int nr = nr0 > nr1 ? nr0 : nr1;
    for (int k0 = 0; k0 < nr; k0 += 8) {
        unsigned vv0[8], vv1[8];
        bool a0 = k0 < nr0, a1 = k0 < nr1;     // wave-uniform branches
        if (a0) {
#pragma unroll
            for (int j = 0; j < 8; j++) {
                int s = (int)e0[k0 + j];       // uniform -> SGPR (s_load)
                vv0[j] = tbs[(size_t)s * 64 + lane];
            }
        }
        if (a1) {
#pragma unroll
            for (int j = 0; j < 8; j++) {
                int s = (int)e1[k0 + j];
                vv1[j] = tbs[(size_t)s * 64 + lane];
            }
        }
        if (a0) {
#pragma unroll
            for (int j = 0; j < 8; j++) {
                ax0 += lo16(vv0[j]);
                ay0 += hi16(vv0[j]);
            }
        }
        if (a1) {
#pragma unroll
            for (int j = 0; j < 8; j++) {
                ax1 += lo16(vv1[j]);
                ay1 += hi16(vv1[j]);
            }
        }
    }
    float2 A = ((const float2*)bnA)[lane];
    float2 B = ((const float2*)bnB)[lane];
    float r0 = fmaxf(fmaf(ax0 * dd0, A.x, B.x), 0.f);
    float r1 = fmaxf(fmaf(ay0 * dd0, A.y, B.y), 0.f);
    float r2 = fmaxf(fmaf(ax1 * dd1, A.x, B.x), 0.f);
    float r3 = fmaxf(fmaf(ay1 * dd1, A.y, B.y), 0.f);
    hout[(size_t)n0 * 64 + lane] = pack2(r0, r1);
    hout[(size_t)n1 * 64 + lane] = pack2(r2, r3);
}

// ---- graph pooling: 1 wave per 32-node chunk, 8-deep load batching -------
#define PN 32
__global__ __launch_bounds__(64) void k_pool(const unsigned* __restrict__ hb,
        const int* __restrict__ batch, float* __restrict__ gsum,
        float* __restrict__ gcnt, const int* __restrict__ flag) {
    int lane = threadIdx.x;
    int f = *flag;
    int s0 = blockIdx.x * PN;                  // NN % PN == 0: no tail
    int cur = geti(batch, s0, f);
    float a0 = 0.f, a1 = 0.f, cn = 0.f;
    auto step = [&](int g, unsigned v) {
        if (g != cur) {                        // wave-uniform branch
            atomicAdd(&gsum[cur * HH + 2 * lane], a0);
            atomicAdd(&gsum[cur * HH + 2 * lane + 1], a1);
            if (lane == 0) atomicAdd(&gcnt[cur], cn);
            a0 = a1 = cn = 0.f; cur = g;
        }
        a0 += lo16(v); a1 += hi16(v); cn += 1.f;
    };
    for (int n = s0; n < s0 + PN; n += 8) {
        int gg[8]; unsigned vv[8];
#pragma unroll
        for (int j = 0; j < 8; j++) {
            gg[j] = geti(batch, n + j, f);
            vv[j] = hb[(size_t)(n + j) * 64 + lane];
        }
#pragma unroll
        for (int j = 0; j < 8; j++) step(gg[j], vv[j]);
    }
    atomicAdd(&gsum[cur * HH + 2 * lane], a0);
    atomicAdd(&gsum[cur * HH + 2 * lane + 1], a1);
    if (lane == 0) atomicAdd(&gcnt[cur], cn);
}

// ---- graph head: one block per graph -------------------------------------
// w1 staged into LDS coalesced (pad stride 129 -> conflict-free reads).
__global__ __launch_bounds__(64) void k_ghead(const float* __restrict__ gsum,
        const float* __restrict__ gcnt, const float* __restrict__ w1,
        const float* __restrict__ b1, const float* __restrict__ w2,
        const float* __restrict__ b2v, float* __restrict__ out) {
    __shared__ float emb[HH];
    __shared__ float w1s[64 * 129];
    int g = blockIdx.x, lane = threadIdx.x;
    for (int gi = lane; gi < 64 * HH; gi += 64)
        w1s[(gi >> 7) * 129 + (gi & 127)] = w1[gi];
    float cn = gcnt[g];
    cn = cn > 1.f ? cn : 1.f;
    float inv = 1.f / cn;
    emb[lane] = gsum[g * HH + lane] * inv;
    emb[lane + 64] = gsum[g * HH + 64 + lane] * inv;
    __syncthreads();
    float acc = b1[lane];
    for (int k = 0; k < HH; k++) acc = fmaf(emb[k], w1s[lane * 129 + k], acc);
    float y = fmaxf(acc, 0.f);
    float v0 = y * w2[lane];
    float v1 = y * w2[64 + lane];
#pragma unroll
    for (int off = 32; off; off >>= 1) {
        v0 += __shfl_xor(v0, off);
        v1 += __shfl_xor(v1, off);
    }
    if (lane == 0) {
        out[(size_t)NN * 2 + g * 2]     = v0 + b2v[0];
        out[(size_t)NN * 2 + g * 2 + 1] = v1 + b2v[1];
    }
}

extern "C" void kernel_launch(void* const* d_in, const int* in_sizes, int n_in,
                              void* d_out, int out_size, void* d_ws, size_t ws_size,
                              hipStream_t stream) {
    const float* x      = (const float*)d_in[0];
    const int*   ei     = (const int*)d_in[1];
    const int*   batch  = (const int*)d_in[2];
    const float* conv_w = (const float*)d_in[3];
    const float* conv_b = (const float*)d_in[4];
    const float* bn_g   = (const float*)d_in[5];
    const float* bn_b   = (const float*)d_in[6];
    const float* bn_m   = (const float*)d_in[7];
    const float* bn_v   = (const float*)d_in[8];
    const float* nw1    = (const float*)d_in[9];
    const float* nb1    = (const float*)d_in[10];
    const float* nw2    = (const float*)d_in[11];
    const float* nb2    = (const float*)d_in[12];
    const float* gw1    = (const float*)d_in[13];
    const float* gb1    = (const float*)d_in[14];
    const float* gw2    = (const float*)d_in[15];
    const float* gb2    = (const float*)d_in[16];
    float* out = (float*)d_out;

    char* ws = (char*)d_ws;
    size_t off = 0;
    auto alloc = [&](size_t bytes) -> void* {
        void* p = ws + off;
        off += (bytes + 255) & ~(size_t)255;
        return p;
    };
    unsigned short* hb   = (unsigned short*)alloc((size_t)NN * HH * 2);       // bf16 h
    unsigned short* tb   = (unsigned short*)alloc((size_t)(NN + 1) * HH * 2); // bf16 t' (+zero row)
    unsigned* chunk  = (unsigned*)alloc((size_t)EE * 4);        // 6.4 MB
    unsigned* csr    = (unsigned*)alloc((size_t)NT * CAP * 4);  // 9.6 MB
    unsigned short* lbu = (unsigned short*)alloc((size_t)NT * CHW * 2); // 306 KB
    int*      offs   = (int*)     alloc((size_t)NN * 4);
    int*      cnt    = (int*)     alloc((size_t)NN * 4);
    float*    dinv   = (float*)   alloc((size_t)NN * 4);
    float*    bnA    = (float*)   alloc((size_t)LL * HH * 4);
    float*    bnB    = (float*)   alloc((size_t)LL * HH * 4);
    float*    gsum   = (float*)   alloc((size_t)GG * HH * 4);
    float*    gcnt   = (float*)   alloc((size_t)GG * 4);
    unsigned short* cwB = (unsigned short*)alloc((size_t)LL * HH * HH * 2);
    unsigned short* n1B = (unsigned short*)alloc((size_t)64 * HH * 2);
    int*      flag   = (int*)     alloc(256);

    // CSR build: coalesced 2-pass (no global atomics), 8-padded segments
    k_part<<<NT, 1024, 0, stream>>>(ei, chunk, lbu, flag, conv_w, nw1, cwB, n1B,
            bnA, bnB, conv_b, bn_g, bn_b, bn_m, bn_v, gsum, gcnt, (unsigned*)tb);
    k_csr<<<NT, 1024, 0, stream>>>(chunk, lbu, csr, offs, cnt, dinv);

    // 3 GCN layers: MFMA gemm (h -> dinv-prescaled bf16 t'), fused
    // aggr+BN+ReLU (t' -> bf16 h)
    k_gemm<float, HH, false><<<(NN + 63) / 64, 256, 0, stream>>>(
        x, cwB, nullptr, tb, 0, dinv, nullptr, nullptr, nullptr);
    k_aggr<<<NN / 8, 256, 0, stream>>>((const unsigned*)tb, csr, offs, cnt,
                                       dinv, bnA, bnB, (unsigned*)hb);
    for (int l = 1; l < LL; l++) {
        k_gemm<unsigned short, HH, false><<<(NN + 63) / 64, 256, 0, stream>>>(
            hb, cwB + (size_t)l * HH * HH, nullptr, tb, 0, dinv,
            nullptr, nullptr, nullptr);
        k_aggr<<<NN / 8, 256, 0, stream>>>((const unsigned*)tb, csr, offs,
                                           cnt, dinv, bnA + l * HH,
                                           bnB + l * HH, (unsigned*)hb);
    }

    // node head fully fused: y2 = relu(h@nw1^T+b1)@nw2^T+b2 in one kernel
    k_gemm<unsigned short, 64, true><<<(NN + 63) / 64, 256, 0, stream>>>(
        hb, n1B, nb1, nullptr, 1, nullptr, nw2, nb2, out);

    // graph head
    k_pool<<<(NN + PN - 1) / PN, 64, 0, stream>>>((const unsigned*)hb, batch,
                                                  gsum, gcnt, flag);
    k_ghead<<<GG, 64, 0, stream>>>(gsum, gcnt, gw1, gb1, gw2, gb2, out);
}